// Round 5
// baseline (11983.934 us; speedup 1.0000x reference)
//
#include <hip/hip_runtime.h>
#include <hip/hip_fp16.h>

#define BATCH 2048
#define TTOT 48
#define TOUT 47
#define SS 128
#define HH 256
#define VV 96
#define MB 8                  // batch rows per block
#define NBLK (BATCH / MB)     // 256 -> one block per CU
#define NTHR 1024             // 16 waves

// ---- workspace layout ----
// ushort (fp16 bits) fragment region, then float region. Total 4,063,232 B.
// GRU frag layout per side-matrix: [pass(2)][kstep(8)][tile(48)][lane(64)][j(8)] fp16
// wc   frag layout:                [pass(2)][kstep(16)][tile(16)][lane(64)][j(8)] fp16
#define F0I_OFF 0             // Wih0 cols 96..351 (768x256)
#define F0H_OFF 393216        // Whh0
#define F1I_OFF 786432        // Wih1
#define F1H_OFF 1179648       // Whh1
#define FC_OFF  1572864       // wcW (256x512)
#define FRAG_USHORTS 1835008
#define TG_OFF 917504         // float offset: [96][768] one-hot columns of Wih0
#define TS_OFF 991232         // float offset: [64][96][4] wsW k-major

typedef __attribute__((ext_vector_type(8))) _Float16 half8v;
typedef __attribute__((ext_vector_type(4))) float f32x4;

__device__ __forceinline__ unsigned short f2h(float f) {
    const __half h = __float2half_rn(f);
    return *reinterpret_cast<const unsigned short*>(&h);
}
__device__ __forceinline__ float h2f(unsigned short u) {
    const __half h = *reinterpret_cast<const __half*>(&u);
    return __half2float(h);
}

struct __align__(16) SMem {
    float ht[MB * 256];              // attentional hidden (fp32, for ws)
    float c0[MB * 256];              // GRU0 state fp32
    float c1[MB * 256];              // GRU1 state fp32 (= "out", for attention)
    float gT[2][MB][776];            // gate pre-acts transposed [side][m][i]; pad 776 breaks banks
    unsigned short htB[2][MB][264];  // fp16 hi/lo fragments of states (264 = 256 + 8 pad)
    unsigned short c0B[2][MB][264];
    unsigned short c1B[2][MB][264];
    unsigned short cxB[2][MB][264];
    float Dp[2][MB];
    float Mp[2][MB];
    int   ym[MB];
};

__device__ __forceinline__ float dot4(const float4 a, const float4 b) {
    return a.x * b.x + a.y * b.y + a.z * b.z + a.w * b.w;
}

// lane l <- lane (l&~15) | ((l+8)&15): pairs col m with col m+8 (DPP row_ror:8, VALU pipe)
__device__ __forceinline__ float ror8f(float v) {
    return __int_as_float(__builtin_amdgcn_update_dpp(0, __float_as_int(v), 0x128, 0xf, 0xf, true));
}

// wave64 sum via DPP; all lanes get total via readlane 63.
__device__ __forceinline__ float wave_sum64(float v) {
    v += __int_as_float(__builtin_amdgcn_update_dpp(0, __float_as_int(v), 0x111, 0xf, 0xf, true));
    v += __int_as_float(__builtin_amdgcn_update_dpp(0, __float_as_int(v), 0x112, 0xf, 0xf, true));
    v += __int_as_float(__builtin_amdgcn_update_dpp(0, __float_as_int(v), 0x114, 0xf, 0xf, true));
    v += __int_as_float(__builtin_amdgcn_update_dpp(0, __float_as_int(v), 0x118, 0xf, 0xf, true));
    v += __int_as_float(__builtin_amdgcn_update_dpp(0, __float_as_int(v), 0x142, 0xa, 0xf, true));
    v += __int_as_float(__builtin_amdgcn_update_dpp(0, __float_as_int(v), 0x143, 0xc, 0xf, true));
    return __int_as_float(__builtin_amdgcn_readlane(__float_as_int(v), 63));
}

// GRU layer GEMV on matrix cores. Waves 0-7: I-side (x input), waves 8-15: H-side.
// Wave wq owns M-tiles {wq, wq+8, ..., wq+40}. B cols 0-7 = state_hi (m), 8-15 = state_lo (m).
// Two chained A-passes (W_hi, W_lo) into one acc -> epilogue col(m)+col(m+8) gives all four
// cross products: (Whi+Wlo)(xhi+xlo) with ~2^-22 representation error per factor.
__device__ __forceinline__ void gru_mfma(
    const unsigned short* __restrict__ F,      // layer frag base (I side at +0, H side at +393216)
    const unsigned short* xB, const unsigned short* hB,  // state frag arrays [2][8][264]
    float* gT, const int tid)
{
    const int w = tid >> 6, lane = tid & 63;
    const int side = w >> 3, wq = w & 7;
    const unsigned short* bst = side ? hB : xB;
    const unsigned short* bp = bst + ((lane >> 3) & 1) * 2112 + (lane & 7) * 264 + ((lane >> 4) << 3);
    half8v Bf[8];
    #pragma unroll
    for (int k = 0; k < 8; ++k) Bf[k] = *(const half8v*)(bp + k * 32);
    const unsigned short* Fw = F + (size_t)side * 393216 + wq * 512 + lane * 8;
    f32x4 acc[6];
    #pragma unroll
    for (int r = 0; r < 6; ++r) acc[r] = (f32x4){0.f, 0.f, 0.f, 0.f};
    #pragma unroll
    for (int pk = 0; pk < 16; ++pk) {          // pass*8 + kstep
        const unsigned short* fa = Fw + (size_t)pk * (48 * 512);
        #pragma unroll
        for (int r = 0; r < 6; ++r) {
            const half8v A = *(const half8v*)(fa + r * (8 * 512));
            acc[r] = __builtin_amdgcn_mfma_f32_16x16x32_f16(A, Bf[pk & 7], acc[r], 0, 0, 0);
        }
    }
    const int colm = lane & 15;
    float* gbase = gT + (size_t)side * 6208 + (lane & 7) * 776 + ((lane >> 4) << 2);
    #pragma unroll
    for (int r = 0; r < 6; ++r) {
        f32x4 s;
        s.x = acc[r].x + ror8f(acc[r].x);
        s.y = acc[r].y + ror8f(acc[r].y);
        s.z = acc[r].z + ror8f(acc[r].z);
        s.w = acc[r].w + ror8f(acc[r].w);
        if (colm < 8) *(f32x4*)(gbase + (wq + r * 8) * 16) = s;
    }
}

__global__ __launch_bounds__(NTHR, 4) void decoder_kernel(
    const int* __restrict__ y,
    const float* __restrict__ enc,
    const float* __restrict__ eh,
    const float* __restrict__ bih0,
    const float* __restrict__ bhh0,
    const float* __restrict__ bih1,
    const float* __restrict__ bhh1,
    const float* __restrict__ wcb,
    const float* __restrict__ wsb,
    const unsigned short* __restrict__ wsU,
    float* __restrict__ out)
{
    __shared__ SMem sm;
    const int tid = threadIdx.x;
    const int b0 = blockIdx.x * MB;
    const float* __restrict__ wsF = (const float*)wsU;
    const float* __restrict__ TG = wsF + TG_OFF;
    const float* __restrict__ TS = wsF + TS_OFF;

    // init: ht=0, c0=eh[0], c1=eh[1] (+ fp16 hi/lo frags)
    for (int p = tid; p < MB * 256; p += NTHR) {
        const int m = p >> 8, c = p & 255;
        sm.ht[p] = 0.f;
        sm.htB[0][m][c] = 0; sm.htB[1][m][c] = 0;
        const float v0 = eh[b0 * HH + p];
        const float v1 = eh[(size_t)BATCH * HH + b0 * HH + p];
        sm.c0[p] = v0; sm.c1[p] = v1;
        const unsigned short h0 = f2h(v0);
        sm.c0B[0][m][c] = h0; sm.c0B[1][m][c] = f2h(v0 - h2f(h0));
        const unsigned short h1 = f2h(v1);
        sm.c1B[0][m][c] = h1; sm.c1B[1][m][c] = f2h(v1 - h2f(h1));
    }
    __syncthreads();

    for (int t = 0; t < TOUT; ++t) {
        if (tid < MB) sm.ym[tid] = y[(b0 + tid) * TTOT + t];

        // ---- GRU0 GEMV (MFMA): x = ht(prev), h = c0
        gru_mfma(wsU + F0I_OFF, &sm.htB[0][0][0], &sm.c0B[0][0][0], &sm.gT[0][0][0], tid);
        __syncthreads();                               // (1) gT + ym ready
        // ---- GRU0 update + c0 frag refresh
        for (int p = tid; p < MB * 256; p += NTHR) {
            const int m = p >> 8, c = p & 255;
            const float* tg = TG + (size_t)sm.ym[m] * 768;
            const float iR = sm.gT[0][m][c]       + bih0[c]       + tg[c];
            const float hR = sm.gT[1][m][c]       + bhh0[c];
            const float iZ = sm.gT[0][m][256 + c] + bih0[256 + c] + tg[256 + c];
            const float hZ = sm.gT[1][m][256 + c] + bhh0[256 + c];
            const float iN = sm.gT[0][m][512 + c] + bih0[512 + c] + tg[512 + c];
            const float hN = sm.gT[1][m][512 + c] + bhh0[512 + c];
            const float r = 1.f / (1.f + __expf(-(iR + hR)));
            const float z = 1.f / (1.f + __expf(-(iZ + hZ)));
            const float n = tanhf(iN + r * hN);
            const float v = (1.f - z) * n + z * sm.c0[p];
            sm.c0[p] = v;
            const unsigned short hb = f2h(v);
            sm.c0B[0][m][c] = hb; sm.c0B[1][m][c] = f2h(v - h2f(hb));
        }
        __syncthreads();                               // (2) c0 ready

        // ---- GRU1 GEMV (MFMA): x = c0(new), h = c1
        gru_mfma(wsU + F1I_OFF, &sm.c0B[0][0][0], &sm.c1B[0][0][0], &sm.gT[0][0][0], tid);
        __syncthreads();                               // (3)
        // ---- GRU1 update + c1 frag refresh
        for (int p = tid; p < MB * 256; p += NTHR) {
            const int m = p >> 8, c = p & 255;
            const float iR = sm.gT[0][m][c]       + bih1[c];
            const float hR = sm.gT[1][m][c]       + bhh1[c];
            const float iZ = sm.gT[0][m][256 + c] + bih1[256 + c];
            const float hZ = sm.gT[1][m][256 + c] + bhh1[256 + c];
            const float iN = sm.gT[0][m][512 + c] + bih1[512 + c];
            const float hN = sm.gT[1][m][512 + c] + bhh1[512 + c];
            const float r = 1.f / (1.f + __expf(-(iR + hR)));
            const float z = 1.f / (1.f + __expf(-(iZ + hZ)));
            const float n = tanhf(iN + r * hN);
            const float v = (1.f - z) * n + z * sm.c1[p];
            sm.c1[p] = v;
            const unsigned short hb = f2h(v);
            sm.c1B[0][m][c] = hb; sm.c1B[1][m][c] = f2h(v - h2f(hb));
        }
        __syncthreads();                               // (4) c1 (= out) ready

        // ---- fused attention: 2 waves per batch row, online softmax, DPP reduce,
        //      single coalesced pass over enc. Partials land in gT.
        {
            const int m = tid >> 7, sh = (tid >> 6) & 1, lane = tid & 63;
            const float4 o4 = *(const float4*)(sm.c1 + m * 256 + lane * 4);
            const float* er = enc + ((size_t)(b0 + m) * SS + sh * 64) * HH + lane * 4;
            float4 C = {0.f, 0.f, 0.f, 0.f};
            float D = 0.f, Mx = -3.0e38f;
            for (int s = 0; s < 64; s += 2) {
                const float4 a4 = *(const float4*)(er);
                const float4 b4 = *(const float4*)(er + HH);
                er += 2 * HH;
                const float e0 = wave_sum64(dot4(a4, o4));
                const float e1 = wave_sum64(dot4(b4, o4));
                const float nm = fmaxf(Mx, fmaxf(e0, e1));
                const float sc = __expf(Mx - nm);
                const float p0 = __expf(e0 - nm);
                const float p1 = __expf(e1 - nm);
                D = D * sc + p0 + p1;
                C.x = C.x * sc + p0 * a4.x + p1 * b4.x;
                C.y = C.y * sc + p0 * a4.y + p1 * b4.y;
                C.z = C.z * sc + p0 * a4.z + p1 * b4.z;
                C.w = C.w * sc + p0 * a4.w + p1 * b4.w;
                Mx = nm;
            }
            *(float4*)(&sm.gT[sh][m][lane * 4]) = C;
            if (lane == 0) { sm.Dp[sh][m] = D; sm.Mp[sh][m] = Mx; }
        }
        __syncthreads();                               // (5) partial C/D/M ready
        // ---- merge s-half softmax states -> cx frags (fp16 hi/lo only; wc consumes frags)
        for (int p = tid; p < MB * 256; p += NTHR) {
            const int m = p >> 8, h = p & 255;
            const float M0 = sm.Mp[0][m], M1 = sm.Mp[1][m];
            const float Mt = fmaxf(M0, M1);
            const float e0 = __expf(M0 - Mt), e1 = __expf(M1 - Mt);
            const float den = sm.Dp[0][m] * e0 + sm.Dp[1][m] * e1;
            const float v = (sm.gT[0][m][h] * e0 + sm.gT[1][m][h] * e1) / den;
            const unsigned short hb = f2h(v);
            sm.cxB[0][m][h] = hb; sm.cxB[1][m][h] = f2h(v - h2f(hb));
        }
        __syncthreads();                               // (6) cx frags ready

        // ---- wc GEMV (MFMA): ht_pre = wcW . [out; ctx], K=512 (ksteps 0-7 c1, 8-15 cx)
        {
            const int w = tid >> 6, lane = tid & 63;
            const unsigned short* b1 = &sm.c1B[0][0][0] + ((lane >> 3) & 1) * 2112 + (lane & 7) * 264 + ((lane >> 4) << 3);
            const unsigned short* b2 = &sm.cxB[0][0][0] + ((lane >> 3) & 1) * 2112 + (lane & 7) * 264 + ((lane >> 4) << 3);
            const unsigned short* FCw = wsU + FC_OFF + w * 512 + lane * 8;
            f32x4 acc = (f32x4){0.f, 0.f, 0.f, 0.f};
            #pragma unroll
            for (int pk = 0; pk < 32; ++pk) {      // pass*16 + kstep
                const int k = pk & 15;
                const unsigned short* bpk = (k < 8) ? (b1 + k * 32) : (b2 + (k - 8) * 32);
                const half8v B = *(const half8v*)bpk;
                const half8v A = *(const half8v*)(FCw + (size_t)pk * (16 * 512));
                acc = __builtin_amdgcn_mfma_f32_16x16x32_f16(A, B, acc, 0, 0, 0);
            }
            f32x4 s;
            s.x = acc.x + ror8f(acc.x);
            s.y = acc.y + ror8f(acc.y);
            s.z = acc.z + ror8f(acc.z);
            s.w = acc.w + ror8f(acc.w);
            if ((lane & 15) < 8)
                *(f32x4*)(&sm.gT[0][lane & 7][w * 16 + ((lane >> 4) << 2)]) = s;
        }
        __syncthreads();                               // (7) wc pre-acts ready
        // ---- wc B: ht = tanh(pre + b) + ht frag refresh
        for (int p = tid; p < MB * 256; p += NTHR) {
            const int m = p >> 8, i = p & 255;
            const float v = tanhf(sm.gT[0][m][i] + wcb[i]);
            sm.ht[p] = v;
            const unsigned short hb = f2h(v);
            sm.htB[0][m][i] = hb; sm.htB[1][m][i] = f2h(v - h2f(hb));
        }
        __syncthreads();                               // (8) ht ready

        // ---- ws: logits from transposed TS (coalesced, VALU)
        for (int p = tid; p < MB * VV; p += NTHR) {
            const int m = p / VV, v = p - m * VV;
            const float* h = sm.ht + m * 256;
            float acc = wsb[v];
            #pragma unroll 4
            for (int k4 = 0; k4 < 64; ++k4)
                acc += dot4(*(const float4*)(TS + ((size_t)k4 * 96 + v) * 4),
                            *(const float4*)(h + k4 * 4));
            out[(size_t)((b0 + m) * TOUT + t) * VV + v] = acc;
        }
        // no end barrier: ws reads only ht (b8); next GEMV0 writes gT (free since b4/b7 use
        // ended before b8) and reads ht/c0 frags (b8/b2-protected).
    }
}

// ---- weight prep: pack fp16 hi/lo MFMA A-fragments + TG/TS float tables ----
__global__ __launch_bounds__(256) void prep_kernel(
    const float* __restrict__ Wih0, const float* __restrict__ Whh0,
    const float* __restrict__ Wih1, const float* __restrict__ Whh1,
    const float* __restrict__ wcW,  const float* __restrict__ wsW,
    unsigned short* __restrict__ wsU)
{
    const int idx = blockIdx.x * 256 + threadIdx.x;
    if (idx < FRAG_USHORTS) {
        const float* src; int stride, koff, nT; int u = idx;
        if (u < F0H_OFF)      { src = Wih0; stride = 352; koff = 96; nT = 48; }
        else if (u < F1I_OFF) { src = Whh0; stride = 256; koff = 0;  nT = 48; u -= F0H_OFF; }
        else if (u < F1H_OFF) { src = Wih1; stride = 256; koff = 0;  nT = 48; u -= F1I_OFF; }
        else if (u < FC_OFF)  { src = Whh1; stride = 256; koff = 0;  nT = 48; u -= F1H_OFF; }
        else                  { src = wcW;  stride = 512; koff = 0;  nT = 16; u -= FC_OFF; }
        const int j = u & 7, l = (u >> 3) & 63;
        const int t2 = u >> 9;
        const int tau = t2 % nT;
        const int pk = t2 / nT;
        const int nK = (nT == 48) ? 8 : 16;
        const int kap = pk % nK, pass = pk / nK;
        const int i = tau * 16 + (l & 15);
        const int k = kap * 32 + ((l >> 4) << 3) + j;
        const float wv = src[(size_t)i * stride + koff + k];
        const unsigned short hb = f2h(wv);
        wsU[idx] = (pass == 0) ? hb : f2h(wv - h2f(hb));
    } else {
        const int f = idx - FRAG_USHORTS;     // 0 .. 98303
        float* wsF = (float*)wsU;
        float val;
        if (f < 73728) {                      // TG[col][i]
            const int col = f / 768, i = f % 768;
            val = Wih0[i * 352 + col];
        } else {                              // TS [64][96][4]
            const int v2 = f - 73728;
            const int j = v2 & 3, q = v2 >> 2;
            const int vv = q % 96, k4 = q / 96;
            val = wsW[vv * 256 + k4 * 4 + j];
        }
        wsF[TG_OFF + f] = val;
    }
}

extern "C" void kernel_launch(void* const* d_in, const int* in_sizes, int n_in,
                              void* d_out, int out_size, void* d_ws, size_t ws_size,
                              hipStream_t stream) {
    (void)in_sizes; (void)n_in; (void)out_size; (void)ws_size;
    const int* y = (const int*)d_in[0];
    const float* enc  = (const float*)d_in[1];
    const float* eh   = (const float*)d_in[2];
    // d_in[3] = is_training (always 1, teacher forcing)
    const float* Wih0 = (const float*)d_in[4];
    const float* Whh0 = (const float*)d_in[5];
    const float* bih0 = (const float*)d_in[6];
    const float* bhh0 = (const float*)d_in[7];
    const float* Wih1 = (const float*)d_in[8];
    const float* Whh1 = (const float*)d_in[9];
    const float* bih1 = (const float*)d_in[10];
    const float* bhh1 = (const float*)d_in[11];
    const float* wcW  = (const float*)d_in[12];
    const float* wcb  = (const float*)d_in[13];
    const float* wsW  = (const float*)d_in[14];
    const float* wsb  = (const float*)d_in[15];
    float* outp = (float*)d_out;
    unsigned short* wsU = (unsigned short*)d_ws;   // needs >= 4,063,232 B

    prep_kernel<<<dim3((FRAG_USHORTS + 98304) / 256), dim3(256), 0, stream>>>(
        Wih0, Whh0, Wih1, Whh1, wcW, wsW, wsU);
    decoder_kernel<<<dim3(NBLK), dim3(NTHR), 0, stream>>>(
        y, enc, eh, bih0, bhh0, bih1, bhh1, wcb, wsb, wsU, outp);
}